// Round 13
// baseline (1084.225 us; speedup 1.0000x reference)
//
#include <hip/hip_runtime.h>
#include <hip/hip_fp16.h>
#include <cstdint>

#define NT 256
#define N_ATOMS_C 600000
#define BATCH_C 24000

constexpr int K_COUNTS[11] = {10000,130000,170000,160000,100000,15000,5000,2500,2500,2500,2500};
constexpr int K_STARTS[11] = {0,10000,140000,310000,470000,570000,585000,590000,592500,595000,597500};
// heavy-degree-first dispatch order
constexpr int DORD[11] = {10,9,8,7,6,5,4,3,2,1,0};

struct AdjPtrs { const int* p[10]; };

typedef float f2 __attribute__((ext_vector_type(2)));

__device__ __forceinline__ float selu_f(float x) {
    const float scale = 1.0507009873554805f;
    const float alpha = 1.6732632423543772f;
    return scale * (x > 0.f ? x : alpha * expm1f(x));
}

__device__ __forceinline__ float2 up2(unsigned u) {
    const __half2 h = __builtin_bit_cast(__half2, u);
    return __half22float2(h);
}
__device__ __forceinline__ unsigned pack2(float a, float b) {
    const __half2 h = __float22half2_rn(make_float2(a, b));
    return __builtin_bit_cast(unsigned, h);
}

// packed dual-FMA: acc += splat(s) * b  (expects v_pk_fma_f32 on CDNA)
__device__ __forceinline__ f2 fma2(float s, f2 b, f2 c) {
    f2 a; a.x = s; a.y = s;
    return __builtin_elementwise_fma(a, b, c);
}

template<int NLD4>
__device__ __forceinline__ void load_row(const uint2* __restrict__ p, float* r) {
#pragma unroll
    for (int v = 0; v < NLD4; ++v) {
        const uint2 t = p[v];
        const float2 a = up2(t.x), b = up2(t.y);
        r[4*v] = a.x; r[4*v+1] = a.y; r[4*v+2] = b.x; r[4*v+3] = b.y;
    }
}
template<int NLD4>
__device__ __forceinline__ void add_row(const uint2* __restrict__ p, float* r) {
#pragma unroll
    for (int v = 0; v < NLD4; ++v) {
        const uint2 t = p[v];
        const float2 a = up2(t.x), b = up2(t.y);
        r[4*v] += a.x; r[4*v+1] += a.y; r[4*v+2] += b.x; r[4*v+3] += b.y;
    }
}
template<int NF, int FO>
__device__ __forceinline__ void fma_strip(const float* r, const float* __restrict__ w,
                                          float* acc) {
#pragma unroll
    for (int f = 0; f < NF; ++f)
#pragma unroll
        for (int o = 0; o < FO; ++o)
            acc[o] = fmaf(r[f], w[f * FO + o], acc[o]);
}

// block -> (degree, segment start, count, tile index within segment)
__device__ __forceinline__ void blk2deg(int blk, int& deg, int& s, int& cnt, int& tile) {
    deg = 0; s = 0; cnt = 0; tile = 0;
#pragma unroll
    for (int di = 0; di < 11; ++di) {
        const int d = DORD[di];
        const int nb = (K_COUNTS[d] + NT - 1) / NT;
        if (blk < nb) { deg = d; s = K_STARTS[d]; cnt = K_COUNTS[d]; tile = blk; return; }
        blk -= nb;
    }
}

// ---------------------------------------------------------------------------
// wpack: W1 (21,75,15) f32 -> padded (21,76,16) f32, zero-filled pads, so
// prep's weight pairs are 8B-aligned f2's at compile-time offsets.
// ---------------------------------------------------------------------------
__global__ __launch_bounds__(256) void wpack_kernel(const float* __restrict__ W,
                                                    float* __restrict__ wpad)
{
    const int idx = blockIdx.x * NT + threadIdx.x;
    if (idx >= 21 * 76 * 16) return;
    const int j = idx / (76 * 16), rem = idx - j * (76 * 16);
    const int f = rem >> 4, o = rem & 15;
    wpad[idx] = (f < 75 && o < 15) ? W[(j * 75 + f) * 15 + o] : 0.f;
}

// ---------------------------------------------------------------------------
// prep: per atom, z_d = x0 @ W[2(d-1)] (d=1..4) into 4 planes (N,16) fp16, and
// s = x0 @ Wb(own deg) + biases (fp16, 32B). Row staged in LDS once (fp16,
// stride 78 shorts -> conflict-free), held in 38 u32 VGPRs; 5 projections
// sequential (8 f2 accs each — no spill). Inner loop: 16 v_pk_fma_f32 + 2 cvt
// per packed feature pair (r12: per-pair fp16 dot fallback -> ~13K VALU/thread,
// 244us at 55% VALUBusy; pk_fma cuts instr count ~2.8x).
// ---------------------------------------------------------------------------
__global__ __launch_bounds__(256) void prep_kernel(
    const float* __restrict__ x0,    // (N, 75) f32
    const float* __restrict__ wpad,  // (21, 76, 16) padded f32
    const float* __restrict__ bias,  // (21, 15)
    const int* __restrict__ mem,
    int* __restrict__ cnt,
    unsigned short* __restrict__ z,  // 4 planes of (N, 16) fp16
    unsigned short* __restrict__ srow) // (N, 16) fp16
{
    __shared__ unsigned short sx[NT * 78];   // 39.9 KB; 39-dword rows (odd)

    int deg, s, c, tile;
    blk2deg(blockIdx.x, deg, s, c, tile);
    const int a0 = tile * NT;
    const int na = min(NT, c - a0);
    const int tid = threadIdx.x;

    // cooperative coalesced stage: na*75 f32 -> fp16 LDS; zero the pad short
    const float* src = x0 + (size_t)(s + a0) * 75;
    for (int i = tid; i < na * 75; i += NT) {
        const int j = i / 75, f = i - j * 75;
        sx[j * 78 + f] = __builtin_bit_cast(unsigned short, __float2half_rn(src[i]));
    }
    for (int j = tid; j < na; j += NT) sx[j * 78 + 75] = 0;
    __syncthreads();

    const int a = a0 + tid;
    if (a >= c) return;                      // no barriers after this point
    const int atom = s + a;

    // pull the whole row into registers (38 u32 = 76 feats incl. zero pad)
    unsigned xr[38];
    {
        const unsigned* row32 = reinterpret_cast<const unsigned*>(sx + tid * 78);
#pragma unroll
        for (int u = 0; u < 38; ++u) xr[u] = row32[u];
    }

    const int wi_b = deg ? (2 * deg - 1) : 20;

#pragma unroll 1
    for (int p = 0; p < 5; ++p) {
        const int wi = (p < 4) ? 2 * p : wi_b;
        const f2* wp = reinterpret_cast<const f2*>(wpad + (size_t)wi * (76 * 16));

        f2 acc2[8];
        if (p < 4) {
#pragma unroll
            for (int q = 0; q < 8; ++q) { acc2[q].x = 0.f; acc2[q].y = 0.f; }
        } else {
#pragma unroll
            for (int q = 0; q < 8; ++q) {
                const int o0 = 2 * q, o1 = 2 * q + 1;
                acc2[q].x = bias[wi_b * 15 + o0] +
                            (deg ? bias[2 * (deg - 1) * 15 + o0] : 0.f);
                acc2[q].y = (o1 < 15) ? (bias[wi_b * 15 + o1] +
                            (deg ? bias[2 * (deg - 1) * 15 + o1] : 0.f)) : 0.f;
            }
        }

#pragma unroll
        for (int u = 0; u < 38; ++u) {
            const float2 xv = up2(xr[u]);
            const f2* wf = wp + (2 * u) * 8;     // feat 2u: 8 pairs
#pragma unroll
            for (int q = 0; q < 8; ++q) acc2[q] = fma2(xv.x, wf[q], acc2[q]);
#pragma unroll
            for (int q = 0; q < 8; ++q) acc2[q] = fma2(xv.y, wf[8 + q], acc2[q]);
        }

        unsigned short* outp = (p < 4)
            ? (z + (size_t)p * (N_ATOMS_C * 16) + (size_t)atom * 16)
            : (srow + (size_t)atom * 16);
        uint4* o4 = reinterpret_cast<uint4*>(outp);
        o4[0] = make_uint4(pack2(acc2[0].x, acc2[0].y), pack2(acc2[1].x, acc2[1].y),
                           pack2(acc2[2].x, acc2[2].y), pack2(acc2[3].x, acc2[3].y));
        o4[1] = make_uint4(pack2(acc2[4].x, acc2[4].y), pack2(acc2[5].x, acc2[5].y),
                           pack2(acc2[6].x, acc2[6].y), pack2(acc2[7].x, 0.f));
    }

    atomicAdd(&cnt[mem[atom]], 1);
}

// ---------------------------------------------------------------------------
// conv1: deg<=4 -> s + sum of gathered 32-B rows (2 x uint4) from z plane.
//        deg>=5 -> s + full x0-row gathers vs Wa (rare: 190K rows).
// ---------------------------------------------------------------------------
__global__ __launch_bounds__(256) void conv1_kernel(
    const float* __restrict__ x0,
    const unsigned short* __restrict__ z,     // 4 planes of (N,16)
    const unsigned short* __restrict__ srow,
    const float* __restrict__ W,
    AdjPtrs adjp,
    unsigned short* __restrict__ y1)  // (N, 16) fp16
{
    int deg, s, c, tile;
    blk2deg(blockIdx.x, deg, s, c, tile);
    const int a = tile * NT + threadIdx.x;
    if (a >= c) return;
    const int atom = s + a;

    float acc[15];
    {
        const uint2* sp = reinterpret_cast<const uint2*>(srow + (size_t)atom * 16);
        float r[16];
        load_row<4>(sp, r);
#pragma unroll
        for (int o = 0; o < 15; ++o) acc[o] = r[o];
    }

    if (deg >= 1 && deg <= 4) {
        const unsigned short* zd = z + (size_t)(deg - 1) * (N_ATOMS_C * 16);
        const int* ad = adjp.p[deg - 1] + (size_t)a * deg;
        int nb[4];
#pragma unroll
        for (int k = 0; k < 4; ++k) nb[k] = ad[k < deg ? k : 0];
        uint4 t[4][2];
#pragma unroll
        for (int k = 0; k < 4; ++k) {
            const uint4* p = reinterpret_cast<const uint4*>(zd + (size_t)nb[k] * 16);
            t[k][0] = p[0]; t[k][1] = p[1];
        }
#pragma unroll
        for (int k = 0; k < 4; ++k) {
            if (k < deg) {
                const unsigned w[8] = {t[k][0].x, t[k][0].y, t[k][0].z, t[k][0].w,
                                       t[k][1].x, t[k][1].y, t[k][1].z, t[k][1].w};
#pragma unroll
                for (int v = 0; v < 8; ++v) {
                    const float2 lo = up2(w[v]);
                    if (2 * v < 15)     acc[2 * v]     += lo.x;
                    if (2 * v + 1 < 15) acc[2 * v + 1] += lo.y;
                }
            }
        }
    } else if (deg >= 5) {
        const float* Wa = W + 2 * (deg - 1) * 1125;
        const int* ad = adjp.p[deg - 1] + (size_t)a * deg;
#pragma unroll 1
        for (int st = 0; st < 3; ++st) {
            float r[25];
#pragma unroll
            for (int j = 0; j < 25; ++j) r[j] = 0.f;
            for (int k = 0; k < deg; ++k) {
                const float* xr = x0 + (size_t)ad[k] * 75 + st * 25;
#pragma unroll
                for (int j = 0; j < 25; ++j) r[j] += xr[j];
            }
            fma_strip<25, 15>(r, Wa + st * 25 * 15, acc);
        }
    }

    uint2* yp = reinterpret_cast<uint2*>(y1 + (size_t)atom * 16);
    float o_[16];
#pragma unroll
    for (int o = 0; o < 16; ++o) o_[o] = (o < 15) ? selu_f(acc[o]) : 0.f;
    yp[0] = make_uint2(pack2(o_[0],o_[1]),  pack2(o_[2],o_[3]));
    yp[1] = make_uint2(pack2(o_[4],o_[5]),  pack2(o_[6],o_[7]));
    yp[2] = make_uint2(pack2(o_[8],o_[9]),  pack2(o_[10],o_[11]));
    yp[3] = make_uint2(pack2(o_[12],o_[13]),pack2(o_[14],o_[15]));
}

// ---------------------------------------------------------------------------
// Generic conv (layers 2-4): thread = atom, fp16 in/out, f32 accum.
// ---------------------------------------------------------------------------
template<int FIN, int FINP, int FO, int FOP, int FS>
__global__ __launch_bounds__(256) void conv_kernel(
    const unsigned short* __restrict__ x,  // (N, FINP) fp16
    const float* __restrict__ W,           // (21, FIN, FO)
    const float* __restrict__ bias,        // (21, FO)
    AdjPtrs adjp,
    unsigned short* __restrict__ y)        // (N, FOP) fp16
{
    static_assert(FS % 4 == 0 && FINP % 4 == 0 && FOP % 4 == 0, "");
    constexpr int NSF = FIN / FS;
    constexpr int TF  = FIN - NSF * FS;
    constexpr int TLD4 = (TF + 3) / 4;
    static_assert(NSF * FS + TLD4 * 4 <= FINP, "tail reads past row");

    int deg, s, c, tile;
    blk2deg(blockIdx.x, deg, s, c, tile);
    const int a = tile * NT + threadIdx.x;
    if (a >= c) return;
    const int atom = s + a;

    const int wi_a = (deg == 0) ? 20 : 2 * (deg - 1);
    const int wi_b = (deg == 0) ? 20 : 2 * deg - 1;
    const float* Wa = W + wi_a * FIN * FO;
    const float* Wb = W + wi_b * FIN * FO;

    float acc[FO];
#pragma unroll
    for (int o = 0; o < FO; ++o)
        acc[o] = bias[wi_b * FO + o] + ((deg > 0) ? bias[wi_a * FO + o] : 0.f);

    const int* myadj = (deg > 0) ? (adjp.p[deg - 1] + (size_t)a * deg) : nullptr;
    const uint2* selfrow = reinterpret_cast<const uint2*>(x + (size_t)atom * FINP);

#pragma unroll 1
    for (int st = 0; st < NSF; ++st) {
        const int f0 = st * FS;
        float r[FS];
        load_row<FS / 4>(selfrow + (f0 >> 2), r);
        fma_strip<FS, FO>(r, Wb + f0 * FO, acc);
        if (deg > 0) {
#pragma unroll
            for (int f = 0; f < FS; ++f) r[f] = 0.f;
            for (int k = 0; k < deg; ++k)
                add_row<FS / 4>(reinterpret_cast<const uint2*>(
                    x + (size_t)myadj[k] * FINP) + (f0 >> 2), r);
            fma_strip<FS, FO>(r, Wa + f0 * FO, acc);
        }
    }
    if constexpr (TF > 0) {
        constexpr int f0 = NSF * FS;
        float r[TLD4 * 4];
        load_row<TLD4>(selfrow + (f0 >> 2), r);
        fma_strip<TF, FO>(r, Wb + f0 * FO, acc);
        if (deg > 0) {
#pragma unroll
            for (int f = 0; f < TLD4 * 4; ++f) r[f] = 0.f;
            for (int k = 0; k < deg; ++k)
                add_row<TLD4>(reinterpret_cast<const uint2*>(
                    x + (size_t)myadj[k] * FINP) + (f0 >> 2), r);
            fma_strip<TF, FO>(r, Wa + f0 * FO, acc);
        }
    }

    float outv[FOP];
#pragma unroll
    for (int o = 0; o < FOP; ++o) outv[o] = (o < FO) ? selu_f(acc[o]) : 0.f;
    uint2* yp = reinterpret_cast<uint2*>(y + (size_t)atom * FOP);
#pragma unroll
    for (int v = 0; v < FOP / 4; ++v)
        yp[v] = make_uint2(pack2(outv[4*v], outv[4*v+1]),
                           pack2(outv[4*v+2], outv[4*v+3]));
}

// ---------------------------------------------------------------------------
// inverted-index build: zero -> (count fused in prep) -> scan -> scatter
// ---------------------------------------------------------------------------
__global__ __launch_bounds__(256) void zero_cnt_kernel(int* __restrict__ cnt) {
    const int i = blockIdx.x * NT + threadIdx.x;
    if (i < BATCH_C) cnt[i] = 0;
}
__global__ __launch_bounds__(1024) void scan_kernel(const int* __restrict__ cnt,
                                                    int* __restrict__ base,
                                                    int* __restrict__ cursor) {
    __shared__ int part[1024];
    const int tid = threadIdx.x;
    constexpr int CH = 24;
    const int i0 = tid * CH;
    int sum = 0;
    for (int j = 0; j < CH; ++j) { const int i = i0 + j; if (i < BATCH_C) sum += cnt[i]; }
    part[tid] = sum;
    __syncthreads();
    for (int off = 1; off < 1024; off <<= 1) {
        const int v = (tid >= off) ? part[tid - off] : 0;
        __syncthreads(); part[tid] += v; __syncthreads();
    }
    int run = part[tid] - sum;
    for (int j = 0; j < CH; ++j) {
        const int i = i0 + j;
        if (i < BATCH_C) { base[i] = run; cursor[i] = run; run += cnt[i]; }
    }
    if (tid == 1023) base[BATCH_C] = part[1023];
}
__global__ __launch_bounds__(256) void scatter_kernel(const int* __restrict__ mem,
                                                      int* __restrict__ cursor,
                                                      int* __restrict__ alist) {
    const int i = blockIdx.x * NT + threadIdx.x;
    if (i < N_ATOMS_C) { const int p = atomicAdd(&cursor[mem[i]], 1); alist[p] = i; }
}

// ---------------------------------------------------------------------------
// one wave per molecule: register sum/max over fp16 y4 rows, fused
// tanh -> 72x24 dense -> pairwise softmax
// ---------------------------------------------------------------------------
__global__ __launch_bounds__(256) void reduce_dense_kernel(
    const unsigned short* __restrict__ y4,  // (N, 36) fp16
    const int* __restrict__ base, const int* __restrict__ alist,
    const float* __restrict__ Wd, const float* __restrict__ bd,
    float* __restrict__ out)
{
    __shared__ float sW[72 * 24];
    __shared__ float sb[24];
    __shared__ float molf[4][72];

    const int tid = threadIdx.x;
    for (int i = tid; i < 72 * 24; i += NT) sW[i] = Wd[i];
    if (tid < 24) sb[tid] = bd[tid];
    __syncthreads();

    const int w = tid >> 6, lane = tid & 63;
    const int mol = blockIdx.x * 4 + w;
    const int b0 = base[mol], b1 = base[mol + 1];

    if (lane < 36) {
        float s = 0.f, mx = -INFINITY;
        for (int k = b0; k < b1; ++k) {
            const int atom = alist[k];
            const float v = __half2float(__builtin_bit_cast(__half,
                                y4[(size_t)atom * 36 + lane]));
            s += v; mx = fmaxf(mx, v);
        }
        molf[w][lane] = tanhf(s);
        molf[w][36 + lane] = tanhf(mx);
    }
    __syncthreads();

    if (lane < 24) {
        float l = sb[lane];
#pragma unroll
        for (int f = 0; f < 72; ++f) l += molf[w][f] * sW[f * 24 + lane];
        const float lp = __shfl_xor(l, 1);
        const float m2 = fmaxf(l, lp);
        const float e = expf(l - m2), ep = expf(lp - m2);
        out[(size_t)mol * 24 + lane] = e / (e + ep);
    }
}

// ---------------------------------------------------------------------------
extern "C" void kernel_launch(void* const* d_in, const int* in_sizes, int n_in,
                              void* d_out, int out_size, void* d_ws, size_t ws_size,
                              hipStream_t stream)
{
    const float* x0         = (const float*)d_in[0];
    const int*   membership = (const int*)d_in[2];
    AdjPtrs adj;
    for (int d = 0; d < 10; ++d) adj.p[d] = (const int*)d_in[3 + d];
    const float *W1=(const float*)d_in[13], *b1=(const float*)d_in[14];
    const float *W2=(const float*)d_in[15], *b2=(const float*)d_in[16];
    const float *W3=(const float*)d_in[17], *b3=(const float*)d_in[18];
    const float *W4=(const float*)d_in[19], *b4=(const float*)d_in[20];
    const float *Wd=(const float*)d_in[21], *bd=(const float*)d_in[22];

    // ws layout (bytes):
    //  A [0 .. 81.6M): z planes 4 x (N,16) fp16 = 76.8M (dead after conv1);
    //                  then y2 = A[0..38.4M) (stride 32), y4 = A[38.4..81.6M)
    //  B [szA .. +38.4M): srow (19.2M) + y1 (19.2M at +19.2M);
    //                  after L2 both dead -> y3 = B[0..38.4M)
    //  ints after B; wpad (padded f32 weights, ~100KB) after ints
    const size_t szA = 81600000;
    const size_t szB = 38400000;
    const size_t nInts = (size_t)N_ATOMS_C + (BATCH_C + 1) + BATCH_C + BATCH_C;
    const size_t wpadOff = szA + szB + nInts * 4;
    if (ws_size < wpadOff + (size_t)21 * 76 * 16 * 4) return;

    char* base0 = (char*)d_ws;
    unsigned short* zbuf = (unsigned short*)base0;
    unsigned short* y2   = (unsigned short*)base0;                      // alias A
    unsigned short* y4   = (unsigned short*)(base0 + 38400000);         // alias A tail
    unsigned short* srow = (unsigned short*)(base0 + szA);
    unsigned short* y1   = (unsigned short*)(base0 + szA + 19200000);
    unsigned short* y3   = (unsigned short*)(base0 + szA);              // alias B after L2
    int* alist  = (int*)(base0 + szA + szB);
    int* base   = alist + N_ATOMS_C;
    int* cursor = base + (BATCH_C + 1);
    int* cnt    = cursor + BATCH_C;
    float* wpad = (float*)(base0 + wpadOff);

    int nblk = 0;
    for (int d = 0; d < 11; ++d) nblk += (K_COUNTS[d] + NT - 1) / NT;
    const int nb_atoms = (N_ATOMS_C + NT - 1) / NT;

    zero_cnt_kernel<<<(BATCH_C + NT - 1) / NT, NT, 0, stream>>>(cnt);
    wpack_kernel<<<(21 * 76 * 16 + NT - 1) / NT, NT, 0, stream>>>(W1, wpad);
    prep_kernel<<<nblk, NT, 0, stream>>>(x0, wpad, b1, membership, cnt, zbuf, srow);
    scan_kernel<<<1, 1024, 0, stream>>>(cnt, base, cursor);
    scatter_kernel<<<nb_atoms, NT, 0, stream>>>(membership, cursor, alist);

    conv1_kernel<<<nblk, NT, 0, stream>>>(x0, zbuf, srow, W1, adj, y1);
    conv_kernel<15,16,20,32,16><<<nblk, NT, 0, stream>>>(y1, W2, b2, adj, y2);
    conv_kernel<20,32,27,32,32><<<nblk, NT, 0, stream>>>(y2, W3, b3, adj, y3);
    conv_kernel<27,32,36,36,32><<<nblk, NT, 0, stream>>>(y3, W4, b4, adj, y4);

    reduce_dense_kernel<<<BATCH_C / 4, NT, 0, stream>>>(y4, base, alist, Wd, bd, (float*)d_out);
}